// Round 5
// baseline (773.973 us; speedup 1.0000x reference)
//
#include <hip/hip_runtime.h>
#include <math.h>

#define NPT 4096
#define NTOT 16384
#define KCAP 192
#define KSTR 193

// ---------------- K0: u[n][c] = sum_d w1[c][d]*s[n][d]; pack w14[c]=w1[c][4] ----
__global__ __launch_bounds__(256) void k0_u(const float* __restrict__ s,
                                            const float* __restrict__ w1,
                                            float* __restrict__ u,
                                            float* __restrict__ w14) {
  int gid = blockIdx.x * 256 + threadIdx.x;
  int n = gid >> 4;
  int c0 = (gid & 15) << 2;
  float4 sv = *(const float4*)(s + (size_t)n * 4);
  float uv[4];
#pragma unroll
  for (int i = 0; i < 4; ++i) {
    const float* wr = w1 + (size_t)(c0 + i) * 5;
    uv[i] = wr[0] * sv.x + wr[1] * sv.y + wr[2] * sv.z + wr[3] * sv.w;
  }
  float4 o; o.x = uv[0]; o.y = uv[1]; o.z = uv[2]; o.w = uv[3];
  *(float4*)(u + (size_t)n * 64 + c0) = o;
  if (blockIdx.x == 0 && threadIdx.x < 64)
    w14[threadIdx.x] = w1[threadIdx.x * 5 + 4];
}

// ---------------- K1: exact KNN (top-16 by (d2, idx) lex) via filter+rank ------
// block: 256 thr = 32 rows x 8 candidate-splits (512 candidates each). grid 512.
__global__ __launch_bounds__(256) void k1_knn(const float* __restrict__ s,
                                              int* __restrict__ knn) {
  __shared__ float d2b[32 * KSTR];
  __shared__ int   idb[32 * KSTR];
  __shared__ int   cnt[32];
  __shared__ int   fincnt[32];
  __shared__ int   anybad;

  const int r = threadIdx.x & 31;
  const int q = threadIdx.x >> 5;
  const int rowg = blockIdx.x * 32 + r;
  const int b = rowg >> 12;
  const float* sb = s + (size_t)b * NPT * 4;
  const float2 pn = *(const float2*)(sb + (size_t)(rowg & 4095) * 4);
  const float sqn = pn.x * pn.x + pn.y * pn.y;

  // density-model threshold: expected count ~32 inside tau
  float tau = __expf(0.5f * sqn) * (1.0f / 64.0f);
  float lo = 0.f, hi = __builtin_inff();
  bool done = false;

  for (int it = 0; it < 40; ++it) {
    if (threadIdx.x < 32) cnt[threadIdx.x] = 0;
    if (threadIdx.x == 0) anybad = 0;
    __syncthreads();  // S1
    if (!done) {
      const int m0 = q * 512;
#pragma unroll 2
      for (int i = 0; i < 512; ++i) {
        int m = m0 + i;
        float2 pm = *(const float2*)(sb + (size_t)m * 4);
        float sqm = pm.x * pm.x + pm.y * pm.y;
        float dot = pn.x * pm.x + pn.y * pm.y;
        float d2 = (sqn + sqm) - 2.f * dot;
        if (d2 < tau) {
          int pos = atomicAdd(&cnt[r], 1);
          if (pos < KCAP) { d2b[r * KSTR + pos] = d2; idb[r * KSTR + pos] = m; }
        }
      }
    }
    __syncthreads();  // S2
    if (!done) {
      int c = cnt[r];
      bool ok = (c >= 16 && c <= KCAP) || (it == 39);
      if (ok) {
        done = true;
        fincnt[r] = (c < KCAP) ? c : KCAP;
      } else {
        atomicAdd(&anybad, 1);
        if (c < 16) { lo = tau; tau = (hi == __builtin_inff()) ? tau * 2.f : 0.5f * (tau + hi); }
        else        { hi = tau; tau = 0.5f * (lo + tau); }
      }
    }
    __syncthreads();  // S3
    int bad = anybad;
    __syncthreads();  // S4 (protects anybad reset next iter)
    if (bad == 0) break;
  }

  // exact selection: rank by lex (d2, idx); rank<16 -> output slot = rank.
  const int c_r = fincnt[r];
  for (int i = q; i < c_r; i += 8) {
    float di = d2b[r * KSTR + i];
    int   ii = idb[r * KSTR + i];
    int rank = 0;
    for (int j = 0; j < c_r; ++j) {
      float dj = d2b[r * KSTR + j];
      int   ij = idb[r * KSTR + j];
      rank += (dj < di || (dj == di && ij < ii)) ? 1 : 0;
    }
    if (rank < 16) knn[(size_t)rowg * 16 + rank] = ii;
  }
}

// ---------------- K2: edge MLP h1 -> h2 -> max-pool; writes node rows ----------
// block: 256 thr, 8 points (128 edge-rows). grid 2048.
#define DOT4ACC(acc, hv, wv) \
  acc = fmaf((hv).x, (wv).x, fmaf((hv).y, (wv).y, fmaf((hv).z, (wv).z, fmaf((hv).w, (wv).w, acc))))

__global__ __launch_bounds__(256) void k2_edge(
    const float* __restrict__ s, const float* __restrict__ g,
    const float* __restrict__ b1, const float* __restrict__ w2g,
    const float* __restrict__ b2, const float* __restrict__ u,
    const float* __restrict__ w14, const int* __restrict__ knn,
    float* __restrict__ node) {
  __shared__ float h1T[128 * 68];
  __shared__ float w2T[128 * 68];
  const int tid = threadIdx.x;

  // stage w2 (128x64) into [o][68]
  for (int gi = tid; gi < 2048; gi += 256) {
    int o = gi >> 4, ct = gi & 15;
    float4 v = *(const float4*)(w2g + (size_t)gi * 4);
    *(float4*)(w2T + o * 68 + ct * 4) = v;
  }

  // producer: h1[row][c] = relu((u_n[c]+b1[c]) - u_m[c] + eye*w14[c])
  {
    const int row = tid >> 1, half = tid & 1, c0 = half * 32;
    const int p = row >> 4, k = row & 15;
    const int n_pt = blockIdx.x * 8 + p;
    const int n_in = n_pt & 4095;
    const int base_b = n_pt - n_in;
    int m_in = knn[(size_t)n_pt * 16 + k] & 4095;  // clamp for safety
    const float eye = (m_in == n_in) ? 1.f : 0.f;
    const float* un = u + (size_t)n_pt * 64 + c0;
    const float* um = u + (size_t)(base_b + m_in) * 64 + c0;
#pragma unroll
    for (int t = 0; t < 8; ++t) {
      float4 a   = *(const float4*)(un + t * 4);
      float4 bb  = *(const float4*)(um + t * 4);
      float4 b1v = *(const float4*)(b1 + c0 + t * 4);
      float4 wv  = *(const float4*)(w14 + c0 + t * 4);
      float4 h;
      h.x = fmaxf(fmaf(eye, wv.x, (a.x + b1v.x) - bb.x), 0.f);
      h.y = fmaxf(fmaf(eye, wv.y, (a.y + b1v.y) - bb.y), 0.f);
      h.z = fmaxf(fmaf(eye, wv.z, (a.z + b1v.z) - bb.z), 0.f);
      h.w = fmaxf(fmaf(eye, wv.w, (a.w + b1v.w) - bb.w), 0.f);
      *(float4*)(h1T + row * 68 + c0 + t * 4) = h;
    }
  }
  __syncthreads();

  // consumer: thread (p = tid>>5, oh = tid&31) owns o = oh + 32j, j<4; 16 k-rows
  {
    const int p = tid >> 5, oh = tid & 31;
    const int n_pt = blockIdx.x * 8 + p;
    float4 acc[16];
    float4 binit;
    binit.x = b2[oh]; binit.y = b2[oh + 32]; binit.z = b2[oh + 64]; binit.w = b2[oh + 96];
#pragma unroll
    for (int kk = 0; kk < 16; ++kk) acc[kk] = binit;

#pragma unroll 4
    for (int ct = 0; ct < 16; ++ct) {
      float4 w0 = *(const float4*)(w2T + (oh      ) * 68 + ct * 4);
      float4 w1v = *(const float4*)(w2T + (oh + 32) * 68 + ct * 4);
      float4 w2v = *(const float4*)(w2T + (oh + 64) * 68 + ct * 4);
      float4 w3v = *(const float4*)(w2T + (oh + 96) * 68 + ct * 4);
#pragma unroll
      for (int kk = 0; kk < 16; ++kk) {
        float4 hv = *(const float4*)(h1T + (p * 16 + kk) * 68 + ct * 4);
        DOT4ACC(acc[kk].x, hv, w0);
        DOT4ACC(acc[kk].y, hv, w1v);
        DOT4ACC(acc[kk].z, hv, w2v);
        DOT4ACC(acc[kk].w, hv, w3v);
      }
    }
    float4 f = acc[0];
#pragma unroll
    for (int kk = 1; kk < 16; ++kk) {
      f.x = fmaxf(f.x, acc[kk].x); f.y = fmaxf(f.y, acc[kk].y);
      f.z = fmaxf(f.z, acc[kk].z); f.w = fmaxf(f.w, acc[kk].w);
    }
    f.x = fmaxf(f.x, 0.f); f.y = fmaxf(f.y, 0.f);
    f.z = fmaxf(f.z, 0.f); f.w = fmaxf(f.w, 0.f);
    float* nrow = node + (size_t)n_pt * 132;
    nrow[oh] = f.x; nrow[oh + 32] = f.y; nrow[oh + 64] = f.z; nrow[oh + 96] = f.w;
    if (oh == 0) {
      float4 sv = *(const float4*)(s + (size_t)n_pt * 4);
      float2 gv = *(const float2*)(g + (size_t)n_pt * 2);
      nrow[128] = sv.x - gv.x; nrow[129] = sv.y - gv.y;
      nrow[130] = sv.z; nrow[131] = sv.w;
    }
  }
}

// ---------------- K3: node MLP 132->64->128->64->4 + sigmoid -------------------
// block: 256 thr, 32 points. grid 512.
__global__ __launch_bounds__(256) void k3_node(
    const float* __restrict__ node,
    const float* __restrict__ fw1, const float* __restrict__ fb1,
    const float* __restrict__ fw2, const float* __restrict__ fb2,
    const float* __restrict__ fw3, const float* __restrict__ fb3,
    const float* __restrict__ fw4, const float* __restrict__ fb4,
    float* __restrict__ out) {
  __shared__ float bufA[32 * 136];
  __shared__ float bufB[32 * 136];
  __shared__ float wb[64 * 136];
  const int tid = threadIdx.x;
  const int n0 = blockIdx.x * 32;
  const int p = tid >> 3, og = tid & 7;

  // stage node rows (132 f32 each) and fw1 (64x132 -> stride 136)
  for (int gi = tid; gi < 32 * 33; gi += 256) {
    int r = gi / 33, ct = gi - r * 33;
    *(float4*)(bufA + r * 136 + ct * 4) = *(const float4*)(node + (size_t)(n0 + r) * 132 + ct * 4);
  }
  for (int gi = tid; gi < 64 * 33; gi += 256) {
    int r = gi / 33, ct = gi - r * 33;
    *(float4*)(wb + r * 136 + ct * 4) = *(const float4*)(fw1 + (size_t)r * 132 + ct * 4);
  }
  __syncthreads();

  // L1: 132 -> 64  (8 outputs/thread, o = og + 8j)
  {
    float acc[8];
#pragma unroll
    for (int j = 0; j < 8; ++j) acc[j] = fb1[og + 8 * j];
    for (int ct = 0; ct < 33; ++ct) {
      float4 in4 = *(const float4*)(bufA + p * 136 + ct * 4);
#pragma unroll
      for (int j = 0; j < 8; ++j) {
        float4 w4 = *(const float4*)(wb + (og + 8 * j) * 136 + ct * 4);
        DOT4ACC(acc[j], in4, w4);
      }
    }
#pragma unroll
    for (int j = 0; j < 8; ++j) bufB[p * 136 + og + 8 * j] = fmaxf(acc[j], 0.f);
  }
  __syncthreads();
  for (int gi = tid; gi < 128 * 16; gi += 256) {  // fw2: 128x64 -> stride 68
    int r = gi >> 4, ct = gi & 15;
    *(float4*)(wb + r * 68 + ct * 4) = *(const float4*)(fw2 + (size_t)r * 64 + ct * 4);
  }
  __syncthreads();

  // L2: 64 -> 128  (16 outputs/thread)
  {
    float acc[16];
#pragma unroll
    for (int j = 0; j < 16; ++j) acc[j] = fb2[og + 8 * j];
    for (int ct = 0; ct < 16; ++ct) {
      float4 in4 = *(const float4*)(bufB + p * 136 + ct * 4);
#pragma unroll
      for (int j = 0; j < 16; ++j) {
        float4 w4 = *(const float4*)(wb + (og + 8 * j) * 68 + ct * 4);
        DOT4ACC(acc[j], in4, w4);
      }
    }
#pragma unroll
    for (int j = 0; j < 16; ++j) bufA[p * 136 + og + 8 * j] = fmaxf(acc[j], 0.f);
  }
  __syncthreads();
  for (int gi = tid; gi < 64 * 32; gi += 256) {  // fw3: 64x128 -> stride 132
    int r = gi >> 5, ct = gi & 31;
    *(float4*)(wb + r * 132 + ct * 4) = *(const float4*)(fw3 + (size_t)r * 128 + ct * 4);
  }
  __syncthreads();

  // L3: 128 -> 64  (8 outputs/thread)
  {
    float acc[8];
#pragma unroll
    for (int j = 0; j < 8; ++j) acc[j] = fb3[og + 8 * j];
    for (int ct = 0; ct < 32; ++ct) {
      float4 in4 = *(const float4*)(bufA + p * 136 + ct * 4);
#pragma unroll
      for (int j = 0; j < 8; ++j) {
        float4 w4 = *(const float4*)(wb + (og + 8 * j) * 132 + ct * 4);
        DOT4ACC(acc[j], in4, w4);
      }
    }
#pragma unroll
    for (int j = 0; j < 8; ++j) bufB[p * 136 + og + 8 * j] = fmaxf(acc[j], 0.f);
  }
  __syncthreads();
  for (int gi = tid; gi < 4 * 16; gi += 256) {  // fw4: 4x64 -> stride 68
    int r = gi >> 4, ct = gi & 15;
    *(float4*)(wb + r * 68 + ct * 4) = *(const float4*)(fw4 + (size_t)r * 64 + ct * 4);
  }
  __syncthreads();

  // L4: 64 -> 4, then out = 2*sigmoid(z) - 1
  if (tid < 128) {
    const int pp = tid >> 2, o = tid & 3;
    float acc = fb4[o];
    for (int ct = 0; ct < 16; ++ct) {
      float4 in4 = *(const float4*)(bufB + pp * 136 + ct * 4);
      float4 w4 = *(const float4*)(wb + o * 68 + ct * 4);
      DOT4ACC(acc, in4, w4);
    }
    float sgm = 1.f / (1.f + expf(-acc));
    out[(size_t)(n0 + pp) * 4 + o] = fmaf(2.f, sgm, -1.f);
  }
}

// ---------------- launch -------------------------------------------------------
extern "C" void kernel_launch(void* const* d_in, const int* in_sizes, int n_in,
                              void* d_out, int out_size, void* d_ws, size_t ws_size,
                              hipStream_t stream) {
  (void)in_sizes; (void)n_in; (void)out_size; (void)ws_size;
  const float* s   = (const float*)d_in[0];
  const float* g   = (const float*)d_in[1];
  const float* w1  = (const float*)d_in[2];
  const float* b1  = (const float*)d_in[3];
  const float* w2  = (const float*)d_in[4];
  const float* b2  = (const float*)d_in[5];
  const float* fw1 = (const float*)d_in[6];
  const float* fb1 = (const float*)d_in[7];
  const float* fw2 = (const float*)d_in[8];
  const float* fb2 = (const float*)d_in[9];
  const float* fw3 = (const float*)d_in[10];
  const float* fb3 = (const float*)d_in[11];
  const float* fw4 = (const float*)d_in[12];
  const float* fb4 = (const float*)d_in[13];

  float* ws   = (float*)d_ws;
  float* u    = ws;                               // 16384*64 = 1048576 f32
  float* w14  = ws + 1048576;                     // 64 f32
  int*   knn  = (int*)(ws + 1048576 + 64);        // 16384*16 i32
  float* node = ws + 1048576 + 64 + 262144;       // 16384*132 f32
  float* out  = (float*)d_out;

  k0_u   <<<1024, 256, 0, stream>>>(s, w1, u, w14);
  k1_knn <<<512,  256, 0, stream>>>(s, knn);
  k2_edge<<<2048, 256, 0, stream>>>(s, g, b1, w2, b2, u, w14, knn, node);
  k3_node<<<512,  256, 0, stream>>>(node, fw1, fb1, fw2, fb2, fw3, fb3, fw4, fb4, out);
}

// Round 6
// 259.400 us; speedup vs baseline: 2.9837x; 2.9837x over previous
//
#include <hip/hip_runtime.h>
#include <math.h>

#define NPT 4096
#define NTOT 16384

// ---------------- K0: u[n][c] = sum_d w1[c][d]*s[n][d]; pack w14[c]=w1[c][4] ----
__global__ __launch_bounds__(256) void k0_u(const float* __restrict__ s,
                                            const float* __restrict__ w1,
                                            float* __restrict__ u,
                                            float* __restrict__ w14) {
  int gid = blockIdx.x * 256 + threadIdx.x;
  int n = gid >> 4;
  int c0 = (gid & 15) << 2;
  float4 sv = *(const float4*)(s + (size_t)n * 4);
  float uv[4];
#pragma unroll
  for (int i = 0; i < 4; ++i) {
    const float* wr = w1 + (size_t)(c0 + i) * 5;
    uv[i] = wr[0] * sv.x + wr[1] * sv.y + wr[2] * sv.z + wr[3] * sv.w;
  }
  float4 o; o.x = uv[0]; o.y = uv[1]; o.z = uv[2]; o.w = uv[3];
  *(float4*)(u + (size_t)n * 64 + c0) = o;
  if (blockIdx.x == 0 && threadIdx.x < 64)
    w14[threadIdx.x] = w1[threadIdx.x * 5 + 4];
}

// ---------------- K1: exact KNN, wave-per-row, register top-16 extraction ------
// block: 256 thr = 4 waves = 4 rows. grid 4096. No LDS, no barriers, no retries.
// Lane l owns candidates m = i*64+l (i=0..63) kept in 64 statically-indexed VGPRs.
// 16 rounds of 64-lane lex-min (d2, m) butterfly == top_k lower-index tie-break.
__global__ __launch_bounds__(256) void k1_knn(const float* __restrict__ s,
                                              unsigned short* __restrict__ knn) {
  const int tid = threadIdx.x;
  const int lane = tid & 63;
  const int row = blockIdx.x * 4 + (tid >> 6);
  const int b = row >> 12, n = row & 4095;
  const float* sb = s + (size_t)b * NPT * 4;
  const float2 pn = *(const float2*)(sb + (size_t)n * 4);
  const float sqn = pn.x * pn.x + pn.y * pn.y;
  const float INF = __builtin_inff();

  float d2v[64];
  float m1v = INF, m2v = INF;
  int m1s = 0, m2s = 0;
#pragma unroll
  for (int i = 0; i < 64; ++i) {
    const int m = i * 64 + lane;
    float2 pm = *(const float2*)(sb + (size_t)m * 4);
    float sqm = pm.x * pm.x + pm.y * pm.y;
    float dot = pn.x * pm.x + pn.y * pm.y;
    float d2 = (sqn + sqm) - 2.f * dot;   // same expression as reference path
    d2v[i] = d2;
    bool c1 = d2 < m1v;
    bool c2 = d2 < m2v;
    m2v = c1 ? m1v : (c2 ? d2 : m2v);
    m2s = c1 ? m1s : (c2 ? i : m2s);
    m1v = c1 ? d2 : m1v;
    m1s = c1 ? i : m1s;
  }

  float lval = m1v;
  int lm = m1s * 64 + lane;
  bool have2 = true;
  unsigned long long emask = 0;

  for (int r = 0; r < 16; ++r) {         // dynamic: keep rescan code un-replicated
    float wv = lval; int wm = lm;
#pragma unroll
    for (int off = 32; off >= 1; off >>= 1) {
      float ov = __shfl_xor(wv, off, 64);
      int   om = __shfl_xor(wm, off, 64);
      bool bet = (ov < wv) || (ov == wv && om < wm);
      wv = bet ? ov : wv;
      wm = bet ? om : wm;
    }
    // all 64 lanes now hold global lex-min (wv, wm); lane r emits it
    if (lane == r) knn[(size_t)row * 16 + r] = (unsigned short)wm;
    // owner lane replaces its local min
    if ((wm & 63) == lane) {
      emask |= 1ull << (wm >> 6);
      if (have2) {
        lval = m2v; lm = m2s * 64 + lane; have2 = false;
      } else {
        float bv = INF; int bs = 0;
#pragma unroll
        for (int i = 0; i < 64; ++i) {
          bool sk = (emask >> i) & 1ull;
          bool bet2 = (!sk) && (d2v[i] < bv);
          bv = bet2 ? d2v[i] : bv;
          bs = bet2 ? i : bs;
        }
        lval = bv; lm = bs * 64 + lane;
      }
    }
  }
}

// ---------------- K2: edge MLP h1 -> h2 -> max-pool; writes node rows ----------
// block: 256 thr, 8 points (128 edge-rows). grid 2048.
#define DOT4ACC(acc, hv, wv) \
  acc = fmaf((hv).x, (wv).x, fmaf((hv).y, (wv).y, fmaf((hv).z, (wv).z, fmaf((hv).w, (wv).w, acc))))

__global__ __launch_bounds__(256) void k2_edge(
    const float* __restrict__ s, const float* __restrict__ g,
    const float* __restrict__ b1, const float* __restrict__ w2g,
    const float* __restrict__ b2, const float* __restrict__ u,
    const float* __restrict__ w14, const unsigned short* __restrict__ knn,
    float* __restrict__ node) {
  __shared__ float h1T[128 * 68];
  __shared__ float w2T[128 * 68];
  const int tid = threadIdx.x;

  // stage w2 (128x64) into [o][68]
  for (int gi = tid; gi < 2048; gi += 256) {
    int o = gi >> 4, ct = gi & 15;
    float4 v = *(const float4*)(w2g + (size_t)gi * 4);
    *(float4*)(w2T + o * 68 + ct * 4) = v;
  }

  // producer: h1[row][c] = relu((u_n[c]+b1[c]) - u_m[c] + eye*w14[c])
  {
    const int row = tid >> 1, half = tid & 1, c0 = half * 32;
    const int p = row >> 4, k = row & 15;
    const int n_pt = blockIdx.x * 8 + p;
    const int n_in = n_pt & 4095;
    const int base_b = n_pt - n_in;
    int m_in = knn[(size_t)n_pt * 16 + k] & 4095;
    const float eye = (m_in == n_in) ? 1.f : 0.f;
    const float* un = u + (size_t)n_pt * 64 + c0;
    const float* um = u + (size_t)(base_b + m_in) * 64 + c0;
#pragma unroll
    for (int t = 0; t < 8; ++t) {
      float4 a   = *(const float4*)(un + t * 4);
      float4 bb  = *(const float4*)(um + t * 4);
      float4 b1v = *(const float4*)(b1 + c0 + t * 4);
      float4 wv  = *(const float4*)(w14 + c0 + t * 4);
      float4 h;
      h.x = fmaxf(fmaf(eye, wv.x, (a.x + b1v.x) - bb.x), 0.f);
      h.y = fmaxf(fmaf(eye, wv.y, (a.y + b1v.y) - bb.y), 0.f);
      h.z = fmaxf(fmaf(eye, wv.z, (a.z + b1v.z) - bb.z), 0.f);
      h.w = fmaxf(fmaf(eye, wv.w, (a.w + b1v.w) - bb.w), 0.f);
      *(float4*)(h1T + row * 68 + c0 + t * 4) = h;
    }
  }
  __syncthreads();

  // consumer: thread (p = tid>>5, oh = tid&31) owns o = oh + 32j, j<4; 16 k-rows
  {
    const int p = tid >> 5, oh = tid & 31;
    const int n_pt = blockIdx.x * 8 + p;
    float4 acc[16];
    float4 binit;
    binit.x = b2[oh]; binit.y = b2[oh + 32]; binit.z = b2[oh + 64]; binit.w = b2[oh + 96];
#pragma unroll
    for (int kk = 0; kk < 16; ++kk) acc[kk] = binit;

#pragma unroll 4
    for (int ct = 0; ct < 16; ++ct) {
      float4 w0 = *(const float4*)(w2T + (oh      ) * 68 + ct * 4);
      float4 w1v = *(const float4*)(w2T + (oh + 32) * 68 + ct * 4);
      float4 w2v = *(const float4*)(w2T + (oh + 64) * 68 + ct * 4);
      float4 w3v = *(const float4*)(w2T + (oh + 96) * 68 + ct * 4);
#pragma unroll
      for (int kk = 0; kk < 16; ++kk) {
        float4 hv = *(const float4*)(h1T + (p * 16 + kk) * 68 + ct * 4);
        DOT4ACC(acc[kk].x, hv, w0);
        DOT4ACC(acc[kk].y, hv, w1v);
        DOT4ACC(acc[kk].z, hv, w2v);
        DOT4ACC(acc[kk].w, hv, w3v);
      }
    }
    float4 f = acc[0];
#pragma unroll
    for (int kk = 1; kk < 16; ++kk) {
      f.x = fmaxf(f.x, acc[kk].x); f.y = fmaxf(f.y, acc[kk].y);
      f.z = fmaxf(f.z, acc[kk].z); f.w = fmaxf(f.w, acc[kk].w);
    }
    f.x = fmaxf(f.x, 0.f); f.y = fmaxf(f.y, 0.f);
    f.z = fmaxf(f.z, 0.f); f.w = fmaxf(f.w, 0.f);
    float* nrow = node + (size_t)n_pt * 132;
    nrow[oh] = f.x; nrow[oh + 32] = f.y; nrow[oh + 64] = f.z; nrow[oh + 96] = f.w;
    if (oh == 0) {
      float4 sv = *(const float4*)(s + (size_t)n_pt * 4);
      float2 gv = *(const float2*)(g + (size_t)n_pt * 2);
      nrow[128] = sv.x - gv.x; nrow[129] = sv.y - gv.y;
      nrow[130] = sv.z; nrow[131] = sv.w;
    }
  }
}

// ---------------- K3: node MLP 132->64->128->64->4 + sigmoid -------------------
// block: 256 thr, 32 points. grid 512.
__global__ __launch_bounds__(256) void k3_node(
    const float* __restrict__ node,
    const float* __restrict__ fw1, const float* __restrict__ fb1,
    const float* __restrict__ fw2, const float* __restrict__ fb2,
    const float* __restrict__ fw3, const float* __restrict__ fb3,
    const float* __restrict__ fw4, const float* __restrict__ fb4,
    float* __restrict__ out) {
  __shared__ float bufA[32 * 136];
  __shared__ float bufB[32 * 136];
  __shared__ float wb[64 * 136];
  const int tid = threadIdx.x;
  const int n0 = blockIdx.x * 32;
  const int p = tid >> 3, og = tid & 7;

  // stage node rows (132 f32 each) and fw1 (64x132 -> stride 136)
  for (int gi = tid; gi < 32 * 33; gi += 256) {
    int r = gi / 33, ct = gi - r * 33;
    *(float4*)(bufA + r * 136 + ct * 4) = *(const float4*)(node + (size_t)(n0 + r) * 132 + ct * 4);
  }
  for (int gi = tid; gi < 64 * 33; gi += 256) {
    int r = gi / 33, ct = gi - r * 33;
    *(float4*)(wb + r * 136 + ct * 4) = *(const float4*)(fw1 + (size_t)r * 132 + ct * 4);
  }
  __syncthreads();

  // L1: 132 -> 64  (8 outputs/thread, o = og + 8j)
  {
    float acc[8];
#pragma unroll
    for (int j = 0; j < 8; ++j) acc[j] = fb1[og + 8 * j];
    for (int ct = 0; ct < 33; ++ct) {
      float4 in4 = *(const float4*)(bufA + p * 136 + ct * 4);
#pragma unroll
      for (int j = 0; j < 8; ++j) {
        float4 w4 = *(const float4*)(wb + (og + 8 * j) * 136 + ct * 4);
        DOT4ACC(acc[j], in4, w4);
      }
    }
#pragma unroll
    for (int j = 0; j < 8; ++j) bufB[p * 136 + og + 8 * j] = fmaxf(acc[j], 0.f);
  }
  __syncthreads();
  for (int gi = tid; gi < 128 * 16; gi += 256) {  // fw2: 128x64 -> stride 68
    int r = gi >> 4, ct = gi & 15;
    *(float4*)(wb + r * 68 + ct * 4) = *(const float4*)(fw2 + (size_t)r * 64 + ct * 4);
  }
  __syncthreads();

  // L2: 64 -> 128  (16 outputs/thread)
  {
    float acc[16];
#pragma unroll
    for (int j = 0; j < 16; ++j) acc[j] = fb2[og + 8 * j];
    for (int ct = 0; ct < 16; ++ct) {
      float4 in4 = *(const float4*)(bufB + p * 136 + ct * 4);
#pragma unroll
      for (int j = 0; j < 16; ++j) {
        float4 w4 = *(const float4*)(wb + (og + 8 * j) * 68 + ct * 4);
        DOT4ACC(acc[j], in4, w4);
      }
    }
#pragma unroll
    for (int j = 0; j < 16; ++j) bufA[p * 136 + og + 8 * j] = fmaxf(acc[j], 0.f);
  }
  __syncthreads();
  for (int gi = tid; gi < 64 * 32; gi += 256) {  // fw3: 64x128 -> stride 132
    int r = gi >> 5, ct = gi & 31;
    *(float4*)(wb + r * 132 + ct * 4) = *(const float4*)(fw3 + (size_t)r * 128 + ct * 4);
  }
  __syncthreads();

  // L3: 128 -> 64  (8 outputs/thread)
  {
    float acc[8];
#pragma unroll
    for (int j = 0; j < 8; ++j) acc[j] = fb3[og + 8 * j];
    for (int ct = 0; ct < 32; ++ct) {
      float4 in4 = *(const float4*)(bufA + p * 136 + ct * 4);
#pragma unroll
      for (int j = 0; j < 8; ++j) {
        float4 w4 = *(const float4*)(wb + (og + 8 * j) * 132 + ct * 4);
        DOT4ACC(acc[j], in4, w4);
      }
    }
#pragma unroll
    for (int j = 0; j < 8; ++j) bufB[p * 136 + og + 8 * j] = fmaxf(acc[j], 0.f);
  }
  __syncthreads();
  for (int gi = tid; gi < 4 * 16; gi += 256) {  // fw4: 4x64 -> stride 68
    int r = gi >> 4, ct = gi & 15;
    *(float4*)(wb + r * 68 + ct * 4) = *(const float4*)(fw4 + (size_t)r * 64 + ct * 4);
  }
  __syncthreads();

  // L4: 64 -> 4, then out = 2*sigmoid(z) - 1
  if (tid < 128) {
    const int pp = tid >> 2, o = tid & 3;
    float acc = fb4[o];
    for (int ct = 0; ct < 16; ++ct) {
      float4 in4 = *(const float4*)(bufB + pp * 136 + ct * 4);
      float4 w4 = *(const float4*)(wb + o * 68 + ct * 4);
      DOT4ACC(acc, in4, w4);
    }
    float sgm = 1.f / (1.f + expf(-acc));
    out[(size_t)(n0 + pp) * 4 + o] = fmaf(2.f, sgm, -1.f);
  }
}

// ---------------- launch -------------------------------------------------------
extern "C" void kernel_launch(void* const* d_in, const int* in_sizes, int n_in,
                              void* d_out, int out_size, void* d_ws, size_t ws_size,
                              hipStream_t stream) {
  (void)in_sizes; (void)n_in; (void)out_size; (void)ws_size;
  const float* s   = (const float*)d_in[0];
  const float* g   = (const float*)d_in[1];
  const float* w1  = (const float*)d_in[2];
  const float* b1  = (const float*)d_in[3];
  const float* w2  = (const float*)d_in[4];
  const float* b2  = (const float*)d_in[5];
  const float* fw1 = (const float*)d_in[6];
  const float* fb1 = (const float*)d_in[7];
  const float* fw2 = (const float*)d_in[8];
  const float* fb2 = (const float*)d_in[9];
  const float* fw3 = (const float*)d_in[10];
  const float* fb3 = (const float*)d_in[11];
  const float* fw4 = (const float*)d_in[12];
  const float* fb4 = (const float*)d_in[13];

  float* ws   = (float*)d_ws;
  float* u    = ws;                                    // 16384*64 = 1048576 f32
  float* w14  = ws + 1048576;                          // 64 f32
  unsigned short* knn16 = (unsigned short*)(ws + 1048576 + 64);  // 262144 u16 = 131072 f32
  float* node = ws + 1048576 + 64 + 131072;            // 16384*132 f32
  float* out  = (float*)d_out;

  k0_u   <<<1024, 256, 0, stream>>>(s, w1, u, w14);
  k1_knn <<<4096, 256, 0, stream>>>(s, knn16);
  k2_edge<<<2048, 256, 0, stream>>>(s, g, b1, w2, b2, u, w14, knn16, node);
  k3_node<<<512,  256, 0, stream>>>(node, fw1, fb1, fw2, fb2, fw3, fb3, fw4, fb4, out);
}